// Round 15
// baseline (588.695 us; speedup 1.0000x reference)
//
#include <hip/hip_runtime.h>
#include <stdint.h>

// AffineCoupling: B=65536 rows, DIM=128, D_IN=64, HID=512, 2 extra hidden layers.
// Fused bf16-MFMA, 32x32x16. 64 rows/block (1024 blocks), 8 waves, 2 blocks/CU
// (68KB LDS, launch_bounds(512,4)). Wave owns 64 neurons (nt=2) x 64 rows (rt=2).
// R15 = R8 (192us best) + three fixes:
//  (1) mov-free ping-pong: explicit aC/aN,bC/bN names + pointer-walked addrs
//      (R8's rotation emitted ~32 v_mov per 4 MFMAs -> VALUBusy 28.6% pacing);
//  (2) K=32 steps: 8 loads feed 16 MFMAs (half the per-step wait overhead);
//  (3) asc/desc k-direction stagger (dir=wave>>2; K-sum commutative): one
//      ascending + one descending wave per SIMD -> load/MFMA phases of
//      co-resident waves decorrelate (anti-convoy), zero extra cost.
// Weights k-major-tiled in d_ws: elem(m,k) -> (m>>5)*tsz + (k>>3)*256 +
// (m&31)*8 + (k&7): an A-frag is ONE contiguous 1KB wave-load.
// LDS h k-major tiled: h[row][n] at byte (n>>3)*1024 + row*16 + (n&7)*2.
// Final (64-neuron) layers: k-split across 8 waves + LDS partial reduce.
// log_s stashed in out's z2 region between s- and t-MLP (same-thread RAW).

#define NROWS 65536
#define RPB   64
#define NBLK  (NROWS / RPB)

// bf16 weight scratch layout (element offsets in d_ws)
#define OFF_S_WIN   0
#define OFF_S_WHID  32768
#define OFF_S_WOUT  557056
#define OFF_T_WIN   589824
#define OFF_T_WHID  622592
#define OFF_T_WOUT  1146880
#define W_ELEMS     1179648

// LDS byte offsets (within per-block dynamic LDS, 69632 B total)
#define P_SCR  0        // final-layer partial tiles: 4 x 4352 B (reuses dead h)
#define SC2    17408    // log_det col-half sums: 128 x 4 B

typedef __attribute__((ext_vector_type(8)))  short short8;
typedef __attribute__((ext_vector_type(4)))  float f32x4;
typedef __attribute__((ext_vector_type(16))) float f32x16;

__device__ __forceinline__ uint32_t f2bf1(float f) {
  uint32_t u = __float_as_uint(f);
  return (u + 0x7fffu + ((u >> 16) & 1u)) >> 16;   // RNE
}
__device__ __forceinline__ uint32_t pk2bf(float a, float b) {
  return f2bf1(a) | (f2bf1(b) << 16);
}

// ---------------- weight fp32 -> bf16 + k-major repack prologue ----------------
__global__ void cvt_weights(const float* __restrict__ sWin, const float* __restrict__ sWhid,
                            const float* __restrict__ sWout, const float* __restrict__ tWin,
                            const float* __restrict__ tWhid, const float* __restrict__ tWout,
                            uint16_t* __restrict__ wbf) {
  int g = blockIdx.x * blockDim.x + threadIdx.x;
  int e = g * 4;
  if (e >= W_ELEMS) return;
  const float* src; int off, base; bool k64;
  if      (e < OFF_S_WHID) { src = sWin;  off = e;              base = OFF_S_WIN;  k64 = true; }
  else if (e < OFF_S_WOUT) { src = sWhid; off = e - OFF_S_WHID; base = OFF_S_WHID; k64 = false; }
  else if (e < OFF_T_WIN)  { src = sWout; off = e - OFF_S_WOUT; base = OFF_S_WOUT; k64 = false; }
  else if (e < OFF_T_WHID) { src = tWin;  off = e - OFF_T_WIN;  base = OFF_T_WIN;  k64 = true; }
  else if (e < OFF_T_WOUT) { src = tWhid; off = e - OFF_T_WHID; base = OFF_T_WHID; k64 = false; }
  else                     { src = tWout; off = e - OFF_T_WOUT; base = OFF_T_WOUT; k64 = false; }
  int m, k, tsz;
  if (k64) { m = off >> 6; k = off & 63;  tsz = 2048;  }
  else     { m = off >> 9; k = off & 511; tsz = 16384; }
  int dest = base + (m >> 5) * tsz + (k >> 3) * 256 + (m & 31) * 8 + (k & 7);
  f32x4 v = *(const f32x4*)(src + off);
  uint2 r; r.x = pk2bf(v.x, v.y); r.y = pk2bf(v.z, v.w);
  *(uint2*)(wbf + dest) = r;
}

// ---------------- A-frag loader ----------------
template<bool BF>
__device__ __forceinline__ short8 ldW(const uint16_t* __restrict__ wb,
                                      const float* __restrict__ wf, int pidx, int oidx) {
  if (BF) {
    return *(const short8*)(wb + pidx);
  } else {
    f32x4 x = *(const f32x4*)(wf + oidx);
    f32x4 y = *(const f32x4*)(wf + oidx + 4);
    short8 r;
    r[0] = (short)f2bf1(x.x); r[1] = (short)f2bf1(x.y);
    r[2] = (short)f2bf1(x.z); r[3] = (short)f2bf1(x.w);
    r[4] = (short)f2bf1(y.x); r[5] = (short)f2bf1(y.y);
    r[6] = (short)f2bf1(y.z); r[7] = (short)f2bf1(y.w);
    return r;
  }
}

#define MFMA32(a, b, c) __builtin_amdgcn_mfma_f32_32x32x16_bf16(a, b, c, 0, 0, 0)

// ---------------- epilogue: bias + relu + pack + k-major LDS store ----------------
// C layout (32x32): col=lane&31=batch row; m=(reg&3)+8*(reg>>2)+4*(lane>>5).
__device__ __forceinline__ void store_h32(f32x16 acc[2][2], const float* __restrict__ bias,
                                          uint16_t* hdst, int wave, int lane) {
  const int l31 = lane & 31, lh = lane >> 5;
  __syncthreads();   // all waves done READING h (h is read+written in place)
  char* wp = (char*)hdst + wave * 8192 + l31 * 16 + lh * 8;
  #pragma unroll
  for (int nt = 0; nt < 2; ++nt) {
    #pragma unroll
    for (int q = 0; q < 4; ++q) {
      const int m0 = wave * 64 + nt * 32 + q * 8 + lh * 4;
      f32x4 bv = *(const f32x4*)(bias + m0);
      #pragma unroll
      for (int rt = 0; rt < 2; ++rt) {
        float v0 = acc[nt][rt][q * 4 + 0] + bv.x;
        float v1 = acc[nt][rt][q * 4 + 1] + bv.y;
        float v2 = acc[nt][rt][q * 4 + 2] + bv.z;
        float v3 = acc[nt][rt][q * 4 + 3] + bv.w;
        uint2 p;
        p.x = pk2bf(fmaxf(v0, 0.f), fmaxf(v1, 0.f));
        p.y = pk2bf(fmaxf(v2, 0.f), fmaxf(v3, 0.f));
        *(uint2*)(wp + nt * 4096 + q * 1024 + rt * 512) = p;
      }
    }
  }
  __syncthreads();
}

// ---------------- layer 1: h = relu(W @ z1^T + b), K=64, B built from global z ----------------
template<bool BF>
__device__ __forceinline__ void dense_in(
    const uint16_t* __restrict__ wb, const float* __restrict__ wf,
    const float* __restrict__ bias, const float* __restrict__ z, long rowbase,
    uint16_t* hdst, int wave, int lane) {
  const int l31 = lane & 31, lh = lane >> 5;
  f32x16 acc[2][2];
  #pragma unroll
  for (int i = 0; i < 2; ++i)
    #pragma unroll
    for (int j = 0; j < 2; ++j) acc[i][j] = (f32x16)0.f;
  #pragma unroll 1
  for (int ks = 0; ks < 4; ++ks) {
    short8 a[2];
    #pragma unroll
    for (int nt = 0; nt < 2; ++nt)
      a[nt] = ldW<BF>(wb, wf,
                      (wave * 2 + nt) * 2048 + (2 * ks + lh) * 256 + l31 * 8,
                      (wave * 64 + nt * 32 + l31) * 64 + ks * 16 + lh * 8);
    #pragma unroll
    for (int rt = 0; rt < 2; ++rt) {
      const float* zp = z + (rowbase + rt * 32 + l31) * 128 + ks * 16 + lh * 8;
      f32x4 u = *(const f32x4*)zp;
      f32x4 v = *(const f32x4*)(zp + 4);
      short8 b;
      b[0] = (short)f2bf1(u.x); b[1] = (short)f2bf1(u.y);
      b[2] = (short)f2bf1(u.z); b[3] = (short)f2bf1(u.w);
      b[4] = (short)f2bf1(v.x); b[5] = (short)f2bf1(v.y);
      b[6] = (short)f2bf1(v.z); b[7] = (short)f2bf1(v.w);
      #pragma unroll
      for (int nt = 0; nt < 2; ++nt)
        acc[nt][rt] = MFMA32(a[nt], b, acc[nt][rt]);
    }
  }
  store_h32(acc, bias, hdst, wave, lane);
}

// ---------------- hidden layer: h = relu(W @ h^T + b), K=512 ----------------
// 16 K=32 steps. Explicit ping-pong (no rotation movs); asc/desc k-direction
// stagger by wave group (sum commutative). 8 loads (4 global + 4 LDS) per
// step feed 16 MFMAs.
#define LDSTEP(AA, BB, pa, pb)                         \
  AA[0] = *(const short8*)((pa));                      \
  AA[1] = *(const short8*)((pa) + 16384);              \
  AA[2] = *(const short8*)((pa) + 512);                \
  AA[3] = *(const short8*)((pa) + 16384 + 512);        \
  BB[0] = *(const short8*)((pb));                      \
  BB[1] = *(const short8*)((pb) + 512);                \
  BB[2] = *(const short8*)((pb) + 2048);               \
  BB[3] = *(const short8*)((pb) + 2048 + 512);

#define MSTEP(AA, BB)                                  \
  __builtin_amdgcn_s_setprio(1);                       \
  acc[0][0] = MFMA32(AA[0], BB[0], acc[0][0]);         \
  acc[0][1] = MFMA32(AA[0], BB[1], acc[0][1]);         \
  acc[1][0] = MFMA32(AA[1], BB[0], acc[1][0]);         \
  acc[1][1] = MFMA32(AA[1], BB[1], acc[1][1]);         \
  acc[0][0] = MFMA32(AA[2], BB[2], acc[0][0]);         \
  acc[0][1] = MFMA32(AA[2], BB[3], acc[0][1]);         \
  acc[1][0] = MFMA32(AA[3], BB[2], acc[1][0]);         \
  acc[1][1] = MFMA32(AA[3], BB[3], acc[1][1]);         \
  __builtin_amdgcn_s_setprio(0);

template<bool BF>
__device__ __forceinline__ void dense_relu512(
    const uint16_t* __restrict__ wb, const float* __restrict__ wf,
    const float* __restrict__ bias, uint16_t* hbuf, int wave, int lane) {
  const int l31 = lane & 31, lh = lane >> 5;
  f32x16 acc[2][2];
  #pragma unroll
  for (int i = 0; i < 2; ++i)
    #pragma unroll
    for (int j = 0; j < 2; ++j) acc[i][j] = (f32x16)0.f;

  if (!BF) {  // fallback: simple loop (correctness only)
    const int wbaseO = (wave * 64 + l31) * 512 + lh * 8;
    const char* bb = (const char*)hbuf + l31 * 16 + lh * 1024;
    #pragma unroll 1
    for (int ks = 0; ks < 32; ++ks) {
      short8 a0 = ldW<false>(wb, wf, 0, wbaseO + ks * 16);
      short8 a1 = ldW<false>(wb, wf, 0, wbaseO + 16384 + ks * 16);
      short8 b0 = *(const short8*)(bb + ks * 2048);
      short8 b1 = *(const short8*)(bb + ks * 2048 + 512);
      acc[0][0] = MFMA32(a0, b0, acc[0][0]);
      acc[0][1] = MFMA32(a0, b1, acc[0][1]);
      acc[1][0] = MFMA32(a1, b0, acc[1][0]);
      acc[1][1] = MFMA32(a1, b1, acc[1][1]);
    }
    store_h32(acc, bias, hbuf, wave, lane);
    return;
  }

  const int dirn = wave >> 2;               // waves 0-3 ascend, 4-7 descend
  const uint16_t* pA = wb + (wave * 2 * 16384 + lh * 256 + l31 * 8) + (dirn ? 15 * 1024 : 0);
  const char*     pB = (const char*)hbuf + lh * 1024 + l31 * 16 + (dirn ? 15 * 4096 : 0);
  const int dAe = dirn ? -1024 : 1024;      // elements per K=32 step
  const int dBb = dirn ? -4096 : 4096;      // bytes per K=32 step

  short8 aC[4], aN[4], bC[4], bN[4];
  LDSTEP(aC, bC, pA, pB)                    // step 0 (in dir order)
  pA += dAe; pB += dBb;

  #pragma unroll 1
  for (int it = 0; it < 8; ++it) {
    LDSTEP(aN, bN, pA, pB)                  // prefetch odd step (always valid)
    MSTEP(aC, bC)                           // compute even step
    const int adv = (it < 7);
    pA += adv ? dAe : 0; pB += adv ? dBb : 0;
    LDSTEP(aC, bC, pA, pB)                  // prefetch next even (redundant at it=7)
    MSTEP(aN, bN)                           // compute odd step
    pA += adv ? dAe : 0; pB += adv ? dBb : 0;
  }
  store_h32(acc, bias, hbuf, wave, lane);
}

// ---------------- final layer partial: 64 neurons, k-split across 8 waves ----------------
// wave w: nt=w&1 (32 neurons), rt=(w>>1)&1 (32 rows), kh=w>>2 (k half).
template<bool BF>
__device__ __forceinline__ void final_partial(
    const uint16_t* __restrict__ wb, const float* __restrict__ wf,
    const uint16_t* hbuf, int nt, int rt, int kh, int lane, f32x16& acc) {
  const int l31 = lane & 31, lh = lane >> 5;
  acc = (f32x16)0.f;
  #pragma unroll 1
  for (int c = 0; c < 4; ++c) {
    #pragma unroll
    for (int j = 0; j < 4; ++j) {
      const int ks = c * 4 + j;
      const int kt = 2 * (kh * 16 + ks) + lh;
      short8 a = ldW<BF>(wb, wf, nt * 16384 + kt * 256 + l31 * 8,
                         (nt * 32 + l31) * 512 + kh * 256 + ks * 16 + lh * 8);
      short8 b = *(const short8*)((const char*)hbuf + kt * 1024 + (rt * 32 + l31) * 16);
      acc = MFMA32(a, b, acc);
    }
  }
}

// ---------------- fused coupling kernel: 64 rows/block, 8 waves, 2 blocks/CU ----------------
template<bool BF>
__global__ __launch_bounds__(512, 4) void coupling(
    const float* __restrict__ z,
    const float* __restrict__ sWin, const float* __restrict__ sbin,
    const float* __restrict__ sWhid, const float* __restrict__ sbhid,
    const float* __restrict__ sWout, const float* __restrict__ sbout,
    const float* __restrict__ tWin, const float* __restrict__ tbin,
    const float* __restrict__ tWhid, const float* __restrict__ tbhid,
    const float* __restrict__ tWout, const float* __restrict__ tbout,
    const uint16_t* __restrict__ wbf, float* __restrict__ out) {
  extern __shared__ __align__(16) uint16_t h[];     // 64KB k-major h + scratch
  const int tid = threadIdx.x;
  const int wave = tid >> 6, lane = tid & 63;
  const int l31 = lane & 31, lh = lane >> 5;
  const long rowbase = (long)blockIdx.x * RPB;
  const int fnt = wave & 1, frt = (wave >> 1) & 1, fkh = wave >> 2;

  // ---------------- s MLP ----------------
  dense_in<BF>(wbf + OFF_S_WIN, sWin, sbin, z, rowbase, h, wave, lane);
  dense_relu512<BF>(wbf + OFF_S_WHID, sWhid, sbhid, h, wave, lane);
  dense_relu512<BF>(wbf + OFF_S_WHID + 262144, sWhid + 262144, sbhid + 512, h, wave, lane);

  // z1 passthrough copy (all waves; independent of h)
  #pragma unroll
  for (int i = 0; i < 2; ++i) {
    int v = tid + i * 512;
    int row = v >> 4, kc = (v & 15) * 4;
    *(f32x4*)(out + (rowbase + row) * 128 + kc) =
        *(const f32x4*)(z + (rowbase + row) * 128 + kc);
  }

  // ---- s final: k-split partials + LDS reduce + clip/stash/logdet ----
  {
    f32x16 fa;
    final_partial<BF>(wbf + OFF_S_WOUT, sWout, h, fnt, frt, fkh, lane, fa);
    __syncthreads();                 // all reads of h done; scratch area reusable
    char* sc = (char*)h + P_SCR + (fnt * 2 + frt) * 4352 + lane * 68;
    if (fkh) {
      #pragma unroll
      for (int q = 0; q < 4; ++q)
        *(f32x4*)(sc + q * 16) = (f32x4){fa[q * 4], fa[q * 4 + 1], fa[q * 4 + 2], fa[q * 4 + 3]};
    }
    __syncthreads();
    if (!fkh) {
      const long row = rowbase + frt * 32 + l31;
      float sum = 0.f;
      #pragma unroll
      for (int q = 0; q < 4; ++q) {
        f32x4 p = *(const f32x4*)(sc + q * 16);
        const int m0 = fnt * 32 + q * 8 + lh * 4;
        f32x4 bv = *(const f32x4*)(sbout + m0);
        f32x4 v;
        v.x = fminf(fmaxf(fa[q * 4 + 0] + p.x + bv.x, -2.f), 2.f);
        v.y = fminf(fmaxf(fa[q * 4 + 1] + p.y + bv.y, -2.f), 2.f);
        v.z = fminf(fmaxf(fa[q * 4 + 2] + p.z + bv.z, -2.f), 2.f);
        v.w = fminf(fmaxf(fa[q * 4 + 3] + p.w + bv.w, -2.f), 2.f);
        sum += v.x + v.y + v.z + v.w;
        *(f32x4*)(out + row * 128 + 64 + m0) = v;   // stash log_s
      }
      sum += __shfl_xor(sum, 32, 64);               // combine lh col-halves
      if (lane < 32)
        *(float*)((char*)h + SC2 + (fnt * 64 + frt * 32 + l31) * 4) = sum;
    }
    __syncthreads();
    if ((wave == 0 || wave == 2) && lane < 32) {    // nt=0, kh=0 waves finish log_det
      float t0 = *(const float*)((char*)h + SC2 + (frt * 32 + l31) * 4);
      float t1 = *(const float*)((char*)h + SC2 + (64 + frt * 32 + l31) * 4);
      out[(long)NROWS * 128 + rowbase + frt * 32 + l31] = t0 + t1;
    }
  }
  __syncthreads();

  // ---------------- t MLP ----------------
  dense_in<BF>(wbf + OFF_T_WIN, tWin, tbin, z, rowbase, h, wave, lane);
  dense_relu512<BF>(wbf + OFF_T_WHID, tWhid, tbhid, h, wave, lane);
  dense_relu512<BF>(wbf + OFF_T_WHID + 262144, tWhid + 262144, tbhid + 512, h, wave, lane);

  // ---- t final: k-split partials + LDS reduce + z2 combine ----
  {
    f32x16 fa;
    final_partial<BF>(wbf + OFF_T_WOUT, tWout, h, fnt, frt, fkh, lane, fa);
    __syncthreads();
    char* sc = (char*)h + P_SCR + (fnt * 2 + frt) * 4352 + lane * 68;
    if (fkh) {
      #pragma unroll
      for (int q = 0; q < 4; ++q)
        *(f32x4*)(sc + q * 16) = (f32x4){fa[q * 4], fa[q * 4 + 1], fa[q * 4 + 2], fa[q * 4 + 3]};
    }
    __syncthreads();
    if (!fkh) {
      const long row = rowbase + frt * 32 + l31;
      #pragma unroll
      for (int q = 0; q < 4; ++q) {
        f32x4 p = *(const f32x4*)(sc + q * 16);
        const int m0 = fnt * 32 + q * 8 + lh * 4;
        f32x4 bv = *(const f32x4*)(tbout + m0);
        f32x4 tv;
        tv.x = fa[q * 4 + 0] + p.x + bv.x;
        tv.y = fa[q * 4 + 1] + p.y + bv.y;
        tv.z = fa[q * 4 + 2] + p.z + bv.z;
        tv.w = fa[q * 4 + 3] + p.w + bv.w;
        const long o = row * 128 + 64 + m0;
        f32x4 ls = *(const f32x4*)(out + o);   // log_s stashed by s-phase (same thread)
        f32x4 z2 = *(const f32x4*)(z + o);
        f32x4 r;
        r.x = z2.x * __expf(ls.x) + tv.x;
        r.y = z2.y * __expf(ls.y) + tv.y;
        r.z = z2.z * __expf(ls.z) + tv.z;
        r.w = z2.w * __expf(ls.w) + tv.w;
        *(f32x4*)(out + o) = r;
      }
    }
  }
}

extern "C" void kernel_launch(void* const* d_in, const int* in_sizes, int n_in,
                              void* d_out, int out_size, void* d_ws, size_t ws_size,
                              hipStream_t stream) {
  const float* z     = (const float*)d_in[0];
  const float* sWin  = (const float*)d_in[1];
  const float* sbin  = (const float*)d_in[2];
  const float* sWhid = (const float*)d_in[3];
  const float* sbhid = (const float*)d_in[4];
  const float* sWout = (const float*)d_in[5];
  const float* sbout = (const float*)d_in[6];
  const float* tWin  = (const float*)d_in[7];
  const float* tbin  = (const float*)d_in[8];
  const float* tWhid = (const float*)d_in[9];
  const float* tbhid = (const float*)d_in[10];
  const float* tWout = (const float*)d_in[11];
  const float* tbout = (const float*)d_in[12];
  float* out = (float*)d_out;
  const size_t lds_bytes = 69632;   // 64KB k-major h + scratch (2 blocks/CU)

  if (ws_size >= (size_t)W_ELEMS * sizeof(uint16_t)) {
    uint16_t* wbf = (uint16_t*)d_ws;
    cvt_weights<<<W_ELEMS / 4 / 256, 256, 0, stream>>>(sWin, sWhid, sWout, tWin, tWhid, tWout, wbf);
    coupling<true><<<NBLK, 512, lds_bytes, stream>>>(z, sWin, sbin, sWhid, sbhid, sWout, sbout,
                                                     tWin, tbin, tWhid, tbhid, tWout, tbout, wbf, out);
  } else {
    coupling<false><<<NBLK, 512, lds_bytes, stream>>>(z, sWin, sbin, sWhid, sbhid, sWout, sbout,
                                                      tWin, tbin, tWhid, tbhid, tWout, tbout,
                                                      (const uint16_t*)d_in[1], out);
  }
}

// Round 16
// 196.250 us; speedup vs baseline: 2.9997x; 2.9997x over previous
//
#include <hip/hip_runtime.h>
#include <stdint.h>

// AffineCoupling: B=65536 rows, DIM=128, D_IN=64, HID=512, 2 extra hidden layers.
// Fused bf16-MFMA, 32x32x16. 64 rows/block (1024 blocks), 8 waves, 2 blocks/CU
// (68KB LDS, launch_bounds(512,4)). Wave owns 64 neurons (nt=2) x 64 rows (rt=2).
// R16 = R8 (192us best) with the K-loop simplified per the R13 evidence
// (prefetch depth 0/1/3 all identical -> TLP does the hiding, not the pipeline):
// K=32 steps, PLAIN load-then-compute, NO double-buffer, NO rotation movs.
// Per step: 8 loads (4 A contiguous-1KB global + 4 B LDS) -> 8 MFMAs.
// Live frags = 8 short8 = 32 VGPRs (fits the 64-arch-VGPR budget at occupancy
// 4 waves/SIMD; R15's 16-frag version spilled 1.6GB -- register arithmetic
// is the binding constraint at (512,4)).
// Weights k-major-tiled in d_ws: elem(m,k) -> (m>>5)*tsz + (k>>3)*256 +
// (m&31)*8 + (k&7): an A-frag is ONE contiguous 1KB wave-load.
// LDS h k-major tiled: h[row][n] at byte (n>>3)*1024 + row*16 + (n&7)*2.
// Final (64-neuron) layers: k-split across 8 waves + LDS partial reduce.
// log_s stashed in out's z2 region between s- and t-MLP (same-thread RAW).

#define NROWS 65536
#define RPB   64
#define NBLK  (NROWS / RPB)

// bf16 weight scratch layout (element offsets in d_ws)
#define OFF_S_WIN   0
#define OFF_S_WHID  32768
#define OFF_S_WOUT  557056
#define OFF_T_WIN   589824
#define OFF_T_WHID  622592
#define OFF_T_WOUT  1146880
#define W_ELEMS     1179648

// LDS byte offsets (within per-block dynamic LDS, 69632 B total)
#define P_SCR  0        // final-layer partial tiles: 4 x 4352 B (reuses dead h)
#define SC2    17408    // log_det col-half sums: 128 x 4 B

typedef __attribute__((ext_vector_type(8)))  short short8;
typedef __attribute__((ext_vector_type(4)))  float f32x4;
typedef __attribute__((ext_vector_type(16))) float f32x16;

__device__ __forceinline__ uint32_t f2bf1(float f) {
  uint32_t u = __float_as_uint(f);
  return (u + 0x7fffu + ((u >> 16) & 1u)) >> 16;   // RNE
}
__device__ __forceinline__ uint32_t pk2bf(float a, float b) {
  return f2bf1(a) | (f2bf1(b) << 16);
}

// ---------------- weight fp32 -> bf16 + k-major repack prologue ----------------
__global__ void cvt_weights(const float* __restrict__ sWin, const float* __restrict__ sWhid,
                            const float* __restrict__ sWout, const float* __restrict__ tWin,
                            const float* __restrict__ tWhid, const float* __restrict__ tWout,
                            uint16_t* __restrict__ wbf) {
  int g = blockIdx.x * blockDim.x + threadIdx.x;
  int e = g * 4;
  if (e >= W_ELEMS) return;
  const float* src; int off, base; bool k64;
  if      (e < OFF_S_WHID) { src = sWin;  off = e;              base = OFF_S_WIN;  k64 = true; }
  else if (e < OFF_S_WOUT) { src = sWhid; off = e - OFF_S_WHID; base = OFF_S_WHID; k64 = false; }
  else if (e < OFF_T_WIN)  { src = sWout; off = e - OFF_S_WOUT; base = OFF_S_WOUT; k64 = false; }
  else if (e < OFF_T_WHID) { src = tWin;  off = e - OFF_T_WIN;  base = OFF_T_WIN;  k64 = true; }
  else if (e < OFF_T_WOUT) { src = tWhid; off = e - OFF_T_WHID; base = OFF_T_WHID; k64 = false; }
  else                     { src = tWout; off = e - OFF_T_WOUT; base = OFF_T_WOUT; k64 = false; }
  int m, k, tsz;
  if (k64) { m = off >> 6; k = off & 63;  tsz = 2048;  }
  else     { m = off >> 9; k = off & 511; tsz = 16384; }
  int dest = base + (m >> 5) * tsz + (k >> 3) * 256 + (m & 31) * 8 + (k & 7);
  f32x4 v = *(const f32x4*)(src + off);
  uint2 r; r.x = pk2bf(v.x, v.y); r.y = pk2bf(v.z, v.w);
  *(uint2*)(wbf + dest) = r;
}

// ---------------- A-frag loader ----------------
template<bool BF>
__device__ __forceinline__ short8 ldW(const uint16_t* __restrict__ wb,
                                      const float* __restrict__ wf, int pidx, int oidx) {
  if (BF) {
    return *(const short8*)(wb + pidx);
  } else {
    f32x4 x = *(const f32x4*)(wf + oidx);
    f32x4 y = *(const f32x4*)(wf + oidx + 4);
    short8 r;
    r[0] = (short)f2bf1(x.x); r[1] = (short)f2bf1(x.y);
    r[2] = (short)f2bf1(x.z); r[3] = (short)f2bf1(x.w);
    r[4] = (short)f2bf1(y.x); r[5] = (short)f2bf1(y.y);
    r[6] = (short)f2bf1(y.z); r[7] = (short)f2bf1(y.w);
    return r;
  }
}

#define MFMA32(a, b, c) __builtin_amdgcn_mfma_f32_32x32x16_bf16(a, b, c, 0, 0, 0)

// ---------------- epilogue: bias + relu + pack + k-major LDS store ----------------
// C layout (32x32): col=lane&31=batch row; m=(reg&3)+8*(reg>>2)+4*(lane>>5).
__device__ __forceinline__ void store_h32(f32x16 acc[2][2], const float* __restrict__ bias,
                                          uint16_t* hdst, int wave, int lane) {
  const int l31 = lane & 31, lh = lane >> 5;
  __syncthreads();   // all waves done READING h (h is read+written in place)
  char* wp = (char*)hdst + wave * 8192 + l31 * 16 + lh * 8;
  #pragma unroll
  for (int nt = 0; nt < 2; ++nt) {
    #pragma unroll
    for (int q = 0; q < 4; ++q) {
      const int m0 = wave * 64 + nt * 32 + q * 8 + lh * 4;
      f32x4 bv = *(const f32x4*)(bias + m0);
      #pragma unroll
      for (int rt = 0; rt < 2; ++rt) {
        float v0 = acc[nt][rt][q * 4 + 0] + bv.x;
        float v1 = acc[nt][rt][q * 4 + 1] + bv.y;
        float v2 = acc[nt][rt][q * 4 + 2] + bv.z;
        float v3 = acc[nt][rt][q * 4 + 3] + bv.w;
        uint2 p;
        p.x = pk2bf(fmaxf(v0, 0.f), fmaxf(v1, 0.f));
        p.y = pk2bf(fmaxf(v2, 0.f), fmaxf(v3, 0.f));
        *(uint2*)(wp + nt * 4096 + q * 1024 + rt * 512) = p;
      }
    }
  }
  __syncthreads();
}

// ---------------- layer 1: h = relu(W @ z1^T + b), K=64, B built from global z ----------------
template<bool BF>
__device__ __forceinline__ void dense_in(
    const uint16_t* __restrict__ wb, const float* __restrict__ wf,
    const float* __restrict__ bias, const float* __restrict__ z, long rowbase,
    uint16_t* hdst, int wave, int lane) {
  const int l31 = lane & 31, lh = lane >> 5;
  f32x16 acc[2][2];
  #pragma unroll
  for (int i = 0; i < 2; ++i)
    #pragma unroll
    for (int j = 0; j < 2; ++j) acc[i][j] = (f32x16)0.f;
  #pragma unroll 1
  for (int ks = 0; ks < 4; ++ks) {
    short8 a[2];
    #pragma unroll
    for (int nt = 0; nt < 2; ++nt)
      a[nt] = ldW<BF>(wb, wf,
                      (wave * 2 + nt) * 2048 + (2 * ks + lh) * 256 + l31 * 8,
                      (wave * 64 + nt * 32 + l31) * 64 + ks * 16 + lh * 8);
    #pragma unroll
    for (int rt = 0; rt < 2; ++rt) {
      const float* zp = z + (rowbase + rt * 32 + l31) * 128 + ks * 16 + lh * 8;
      f32x4 u = *(const f32x4*)zp;
      f32x4 v = *(const f32x4*)(zp + 4);
      short8 b;
      b[0] = (short)f2bf1(u.x); b[1] = (short)f2bf1(u.y);
      b[2] = (short)f2bf1(u.z); b[3] = (short)f2bf1(u.w);
      b[4] = (short)f2bf1(v.x); b[5] = (short)f2bf1(v.y);
      b[6] = (short)f2bf1(v.z); b[7] = (short)f2bf1(v.w);
      #pragma unroll
      for (int nt = 0; nt < 2; ++nt)
        acc[nt][rt] = MFMA32(a[nt], b, acc[nt][rt]);
    }
  }
  store_h32(acc, bias, hdst, wave, lane);
}

// ---------------- hidden layer: h = relu(W @ h^T + b), K=512 ----------------
// 16 K=32 steps, plain load-then-compute (no double-buffer; TLP hides latency
// -- R13 showed prefetch depth is irrelevant). 8 loads -> 8 MFMAs per step.
// Live frags: 8 short8 = 32 VGPRs, safely inside the 64-arch-VGPR budget.
template<bool BF>
__device__ __forceinline__ void dense_relu512(
    const uint16_t* __restrict__ wb, const float* __restrict__ wf,
    const float* __restrict__ bias, uint16_t* hbuf, int wave, int lane) {
  const int l31 = lane & 31, lh = lane >> 5;
  f32x16 acc[2][2];
  #pragma unroll
  for (int i = 0; i < 2; ++i)
    #pragma unroll
    for (int j = 0; j < 2; ++j) acc[i][j] = (f32x16)0.f;
  const int wbaseP = wave * 2 * 16384 + lh * 256 + l31 * 8;   // + nt*16384 + ks*512
  const int wbaseO = (wave * 64 + l31) * 512 + lh * 8;        // + nt*32*512 + ks*16
  const char* bb = (const char*)hbuf + l31 * 16 + lh * 1024;  // + ks*2048 + rt*512

  #pragma unroll 1
  for (int s = 0; s < 16; ++s) {
    const int k0 = 2 * s, k1 = 2 * s + 1;
    short8 a00 = ldW<BF>(wb, wf, wbaseP + k0 * 512,         wbaseO + k0 * 16);
    short8 a10 = ldW<BF>(wb, wf, wbaseP + 16384 + k0 * 512, wbaseO + 16384 + k0 * 16);
    short8 a01 = ldW<BF>(wb, wf, wbaseP + k1 * 512,         wbaseO + k1 * 16);
    short8 a11 = ldW<BF>(wb, wf, wbaseP + 16384 + k1 * 512, wbaseO + 16384 + k1 * 16);
    short8 b00 = *(const short8*)(bb + k0 * 2048);
    short8 b10 = *(const short8*)(bb + k0 * 2048 + 512);
    short8 b01 = *(const short8*)(bb + k1 * 2048);
    short8 b11 = *(const short8*)(bb + k1 * 2048 + 512);
    __builtin_amdgcn_s_setprio(1);
    acc[0][0] = MFMA32(a00, b00, acc[0][0]);
    acc[0][1] = MFMA32(a00, b10, acc[0][1]);
    acc[1][0] = MFMA32(a10, b00, acc[1][0]);
    acc[1][1] = MFMA32(a10, b10, acc[1][1]);
    acc[0][0] = MFMA32(a01, b01, acc[0][0]);
    acc[0][1] = MFMA32(a01, b11, acc[0][1]);
    acc[1][0] = MFMA32(a11, b01, acc[1][0]);
    acc[1][1] = MFMA32(a11, b11, acc[1][1]);
    __builtin_amdgcn_s_setprio(0);
  }
  store_h32(acc, bias, hbuf, wave, lane);
}

// ---------------- final layer partial: 64 neurons, k-split across 8 waves ----------------
// wave w: nt=w&1 (32 neurons), rt=(w>>1)&1 (32 rows), kh=w>>2 (k half).
template<bool BF>
__device__ __forceinline__ void final_partial(
    const uint16_t* __restrict__ wb, const float* __restrict__ wf,
    const uint16_t* hbuf, int nt, int rt, int kh, int lane, f32x16& acc) {
  const int l31 = lane & 31, lh = lane >> 5;
  acc = (f32x16)0.f;
  #pragma unroll 1
  for (int c = 0; c < 4; ++c) {
    #pragma unroll
    for (int j = 0; j < 4; ++j) {
      const int ks = c * 4 + j;
      const int kt = 2 * (kh * 16 + ks) + lh;
      short8 a = ldW<BF>(wb, wf, nt * 16384 + kt * 256 + l31 * 8,
                         (nt * 32 + l31) * 512 + kh * 256 + ks * 16 + lh * 8);
      short8 b = *(const short8*)((const char*)hbuf + kt * 1024 + (rt * 32 + l31) * 16);
      acc = MFMA32(a, b, acc);
    }
  }
}

// ---------------- fused coupling kernel: 64 rows/block, 8 waves, 2 blocks/CU ----------------
template<bool BF>
__global__ __launch_bounds__(512, 4) void coupling(
    const float* __restrict__ z,
    const float* __restrict__ sWin, const float* __restrict__ sbin,
    const float* __restrict__ sWhid, const float* __restrict__ sbhid,
    const float* __restrict__ sWout, const float* __restrict__ sbout,
    const float* __restrict__ tWin, const float* __restrict__ tbin,
    const float* __restrict__ tWhid, const float* __restrict__ tbhid,
    const float* __restrict__ tWout, const float* __restrict__ tbout,
    const uint16_t* __restrict__ wbf, float* __restrict__ out) {
  extern __shared__ __align__(16) uint16_t h[];     // 64KB k-major h + scratch
  const int tid = threadIdx.x;
  const int wave = tid >> 6, lane = tid & 63;
  const int l31 = lane & 31, lh = lane >> 5;
  const long rowbase = (long)blockIdx.x * RPB;
  const int fnt = wave & 1, frt = (wave >> 1) & 1, fkh = wave >> 2;

  // ---------------- s MLP ----------------
  dense_in<BF>(wbf + OFF_S_WIN, sWin, sbin, z, rowbase, h, wave, lane);
  dense_relu512<BF>(wbf + OFF_S_WHID, sWhid, sbhid, h, wave, lane);
  dense_relu512<BF>(wbf + OFF_S_WHID + 262144, sWhid + 262144, sbhid + 512, h, wave, lane);

  // z1 passthrough copy (all waves; independent of h)
  #pragma unroll
  for (int i = 0; i < 2; ++i) {
    int v = tid + i * 512;
    int row = v >> 4, kc = (v & 15) * 4;
    *(f32x4*)(out + (rowbase + row) * 128 + kc) =
        *(const f32x4*)(z + (rowbase + row) * 128 + kc);
  }

  // ---- s final: k-split partials + LDS reduce + clip/stash/logdet ----
  {
    f32x16 fa;
    final_partial<BF>(wbf + OFF_S_WOUT, sWout, h, fnt, frt, fkh, lane, fa);
    __syncthreads();                 // all reads of h done; scratch area reusable
    char* sc = (char*)h + P_SCR + (fnt * 2 + frt) * 4352 + lane * 68;
    if (fkh) {
      #pragma unroll
      for (int q = 0; q < 4; ++q)
        *(f32x4*)(sc + q * 16) = (f32x4){fa[q * 4], fa[q * 4 + 1], fa[q * 4 + 2], fa[q * 4 + 3]};
    }
    __syncthreads();
    if (!fkh) {
      const long row = rowbase + frt * 32 + l31;
      float sum = 0.f;
      #pragma unroll
      for (int q = 0; q < 4; ++q) {
        f32x4 p = *(const f32x4*)(sc + q * 16);
        const int m0 = fnt * 32 + q * 8 + lh * 4;
        f32x4 bv = *(const f32x4*)(sbout + m0);
        f32x4 v;
        v.x = fminf(fmaxf(fa[q * 4 + 0] + p.x + bv.x, -2.f), 2.f);
        v.y = fminf(fmaxf(fa[q * 4 + 1] + p.y + bv.y, -2.f), 2.f);
        v.z = fminf(fmaxf(fa[q * 4 + 2] + p.z + bv.z, -2.f), 2.f);
        v.w = fminf(fmaxf(fa[q * 4 + 3] + p.w + bv.w, -2.f), 2.f);
        sum += v.x + v.y + v.z + v.w;
        *(f32x4*)(out + row * 128 + 64 + m0) = v;   // stash log_s
      }
      sum += __shfl_xor(sum, 32, 64);               // combine lh col-halves
      if (lane < 32)
        *(float*)((char*)h + SC2 + (fnt * 64 + frt * 32 + l31) * 4) = sum;
    }
    __syncthreads();
    if ((wave == 0 || wave == 2) && lane < 32) {    // nt=0, kh=0 waves finish log_det
      float t0 = *(const float*)((char*)h + SC2 + (frt * 32 + l31) * 4);
      float t1 = *(const float*)((char*)h + SC2 + (64 + frt * 32 + l31) * 4);
      out[(long)NROWS * 128 + rowbase + frt * 32 + l31] = t0 + t1;
    }
  }
  __syncthreads();

  // ---------------- t MLP ----------------
  dense_in<BF>(wbf + OFF_T_WIN, tWin, tbin, z, rowbase, h, wave, lane);
  dense_relu512<BF>(wbf + OFF_T_WHID, tWhid, tbhid, h, wave, lane);
  dense_relu512<BF>(wbf + OFF_T_WHID + 262144, tWhid + 262144, tbhid + 512, h, wave, lane);

  // ---- t final: k-split partials + LDS reduce + z2 combine ----
  {
    f32x16 fa;
    final_partial<BF>(wbf + OFF_T_WOUT, tWout, h, fnt, frt, fkh, lane, fa);
    __syncthreads();
    char* sc = (char*)h + P_SCR + (fnt * 2 + frt) * 4352 + lane * 68;
    if (fkh) {
      #pragma unroll
      for (int q = 0; q < 4; ++q)
        *(f32x4*)(sc + q * 16) = (f32x4){fa[q * 4], fa[q * 4 + 1], fa[q * 4 + 2], fa[q * 4 + 3]};
    }
    __syncthreads();
    if (!fkh) {
      const long row = rowbase + frt * 32 + l31;
      #pragma unroll
      for (int q = 0; q < 4; ++q) {
        f32x4 p = *(const f32x4*)(sc + q * 16);
        const int m0 = fnt * 32 + q * 8 + lh * 4;
        f32x4 bv = *(const f32x4*)(tbout + m0);
        f32x4 tv;
        tv.x = fa[q * 4 + 0] + p.x + bv.x;
        tv.y = fa[q * 4 + 1] + p.y + bv.y;
        tv.z = fa[q * 4 + 2] + p.z + bv.z;
        tv.w = fa[q * 4 + 3] + p.w + bv.w;
        const long o = row * 128 + 64 + m0;
        f32x4 ls = *(const f32x4*)(out + o);   // log_s stashed by s-phase (same thread)
        f32x4 z2 = *(const f32x4*)(z + o);
        f32x4 r;
        r.x = z2.x * __expf(ls.x) + tv.x;
        r.y = z2.y * __expf(ls.y) + tv.y;
        r.z = z2.z * __expf(ls.z) + tv.z;
        r.w = z2.w * __expf(ls.w) + tv.w;
        *(f32x4*)(out + o) = r;
      }
    }
  }
}

extern "C" void kernel_launch(void* const* d_in, const int* in_sizes, int n_in,
                              void* d_out, int out_size, void* d_ws, size_t ws_size,
                              hipStream_t stream) {
  const float* z     = (const float*)d_in[0];
  const float* sWin  = (const float*)d_in[1];
  const float* sbin  = (const float*)d_in[2];
  const float* sWhid = (const float*)d_in[3];
  const float* sbhid = (const float*)d_in[4];
  const float* sWout = (const float*)d_in[5];
  const float* sbout = (const float*)d_in[6];
  const float* tWin  = (const float*)d_in[7];
  const float* tbin  = (const float*)d_in[8];
  const float* tWhid = (const float*)d_in[9];
  const float* tbhid = (const float*)d_in[10];
  const float* tWout = (const float*)d_in[11];
  const float* tbout = (const float*)d_in[12];
  float* out = (float*)d_out;
  const size_t lds_bytes = 69632;   // 64KB k-major h + scratch (2 blocks/CU)

  if (ws_size >= (size_t)W_ELEMS * sizeof(uint16_t)) {
    uint16_t* wbf = (uint16_t*)d_ws;
    cvt_weights<<<W_ELEMS / 4 / 256, 256, 0, stream>>>(sWin, sWhid, sWout, tWin, tWhid, tWout, wbf);
    coupling<true><<<NBLK, 512, lds_bytes, stream>>>(z, sWin, sbin, sWhid, sbhid, sWout, sbout,
                                                     tWin, tbin, tWhid, tbhid, tWout, tbout, wbf, out);
  } else {
    coupling<false><<<NBLK, 512, lds_bytes, stream>>>(z, sWin, sbin, sWhid, sbhid, sWout, sbout,
                                                      tWin, tbin, tWhid, tbhid, tWout, tbout,
                                                      (const uint16_t*)d_in[1], out);
  }
}